// Round 7
// baseline (404.936 us; speedup 1.0000x reference)
//
#include <hip/hip_runtime.h>
#include <math.h>

// Problem constants (from reference)
#define BATCH 4
#define HW 512
#define NPLANE (512 * 512)
#define NS 12288      // oversampled points per batch
#define NU 3072       // top-k uncertain selected
#define NR 1024       // random extra points
#define NP 4096       // total selected points per batch
#define CF_CH 64
#define CC_CH 128
#define CIN 192
#define HID 256
#define OUTC 4
#define M_TOT (BATCH * NP)  // 16384
#define GCH_SPLIT 4         // point-chunks per (batch, channel) in gather

// ---------------------------------------------------------------------------
// Bit-exact replication of XLA:CPU's vectorized f32 expf (Cephes polynomial),
// strict per-op f32 rounding, no FMA. DO NOT TOUCH — top-k order depends on it.
// ---------------------------------------------------------------------------
__device__ __forceinline__ float xla_expf(float xin) {
  float x = fminf(fmaxf(xin, -88.3762626647949f), 88.3762626647950f);
  float fx = floorf(__fadd_rn(__fmul_rn(x, 1.44269504088896341f), 0.5f));
  float tmp = __fmul_rn(0.693359375f, fx);
  float z = __fmul_rn(-2.12194440e-4f, fx);
  x = __fsub_rn(__fsub_rn(x, tmp), z);
  float y = __fadd_rn(__fmul_rn(x, 1.9875691500E-4f), 1.3981999507E-3f);
  y = __fadd_rn(__fmul_rn(y, x), 8.3334519073E-3f);
  y = __fadd_rn(__fmul_rn(y, x), 4.1665795894E-2f);
  y = __fadd_rn(__fmul_rn(y, x), 1.6666665459E-1f);
  y = __fadd_rn(__fmul_rn(y, x), 5.0000001201E-1f);
  z = __fmul_rn(x, x);
  y = __fadd_rn(__fmul_rn(y, z), x);
  y = __fadd_rn(y, 1.0f);
  int n = (int)fx;
  float p2n = __int_as_float((n + 127) << 23);
  return __fmul_rn(y, p2n);
}

// ---------------------------------------------------------------------------
// K1: uncertainty at oversampled points (bit-replicates reference f32 chain)
// fused with the random-extra point append (disjoint thread range).
// ---------------------------------------------------------------------------
__global__ void k_uncert_extra(const float* __restrict__ logits,
                               const float* __restrict__ rp,
                               const float* __restrict__ re,
                               float* __restrict__ u,
                               float* __restrict__ pts_out) {
  int gid = blockIdx.x * 256 + threadIdx.x;
  if (gid < BATCH * NS) {
    int b = gid / NS;
    float px = rp[(size_t)gid * 2 + 0];
    float py = rp[(size_t)gid * 2 + 1];
    const float* plane = logits + (size_t)b * OUTC * NPLANE;  // channel 0

    float x = __fsub_rn(__fmul_rn(px, 512.0f), 0.5f);
    float y = __fsub_rn(__fmul_rn(py, 512.0f), 0.5f);
    float x0f = floorf(x), y0f = floorf(y);
    float wx = __fsub_rn(x, x0f);
    float wy = __fsub_rn(y, y0f);
    int x0 = (int)x0f, y0 = (int)y0f;
    int x1 = x0 + 1, y1 = y0 + 1;
    bool vx0 = (x0 >= 0) & (x0 < HW);
    bool vx1 = (x1 >= 0) & (x1 < HW);
    bool vy0 = (y0 >= 0) & (y0 < HW);
    bool vy1 = (y1 >= 0) & (y1 < HW);
    float g00 = (vx0 && vy0) ? plane[y0 * HW + x0] : 0.0f;
    float g10 = (vx1 && vy0) ? plane[y0 * HW + x1] : 0.0f;
    float g01 = (vx0 && vy1) ? plane[y1 * HW + x0] : 0.0f;
    float g11 = (vx1 && vy1) ? plane[y1 * HW + x1] : 0.0f;
    float omx = __fsub_rn(1.0f, wx);
    float omy = __fsub_rn(1.0f, wy);
    float w00 = __fmul_rn(omx, omy);
    float w10 = __fmul_rn(wx, omy);
    float w01 = __fmul_rn(omx, wy);
    float w11 = __fmul_rn(wx, wy);
    float s = __fadd_rn(
        __fadd_rn(__fadd_rn(__fmul_rn(g00, w00), __fmul_rn(g10, w10)),
                  __fmul_rn(g01, w01)),
        __fmul_rn(g11, w11));
    float e = xla_expf(-s);
    float sig = __fdiv_rn(1.0f, __fadd_rn(1.0f, e));
    float t = __fmul_rn(fabsf(__fsub_rn(sig, 0.5f)), 2.0f);
    u[gid] = __fsub_rn(1.0f, t);
  } else {
    int g = gid - BATCH * NS;  // [0, BATCH*NR)
    if (g < BATCH * NR) {
      int b = g / NR, j = g - b * NR;
      pts_out[((size_t)b * NP + NU + j) * 2 + 0] = re[(size_t)g * 2 + 0];
      pts_out[((size_t)b * NP + NU + j) * 2 + 1] = re[(size_t)g * 2 + 1];
    }
  }
}

// ---------------------------------------------------------------------------
// K2: exact stable top-k via ranking. Same split-predicate compares as the
// R6-verified kernel (bit-identical counting), but candidates are read via
// wave-uniform GLOBAL loads (L1/L2-cached broadcast; scalar-load eligible)
// instead of staging all of u in LDS — the uniform ds_read_b128 stream was
// LDS-pipe-bound (~12 cyc/instr serialized per CU).
//   j <  wave_base       : (u_j>u_i)||(u_j==u_i && j<i)  ==  (u_j >= u_i)
//   j in [wb, wb+64)     : full original predicate (includes j==i -> 0)
//   j >= wave_base + 64  : ==  (u_j > u_i)
// ---------------------------------------------------------------------------
__global__ __launch_bounds__(256) void k_select(const float* __restrict__ u,
                                                const float* __restrict__ rp,
                                                float* __restrict__ pts_out) {
  int b = blockIdx.x / (NS / 256);
  int blk = blockIdx.x % (NS / 256);
  const float* __restrict__ ub = u + (size_t)b * NS;
  int i = blk * 256 + (int)threadIdx.x;
  int wb = i & ~63;  // wave-uniform (blk*256 is 64-aligned)
  float ui = ub[i];
  int r0 = 0, r1 = 0, r2 = 0, r3 = 0;
  // Phase A: j < wb  ->  count (u[j] >= ui); 16 candidates/iter, uniform loads
  for (int j = 0; j < wb; j += 16) {
    float4 v0 = *(const float4*)&ub[j];
    float4 v1 = *(const float4*)&ub[j + 4];
    float4 v2 = *(const float4*)&ub[j + 8];
    float4 v3 = *(const float4*)&ub[j + 12];
    r0 += (v0.x >= ui) + (v1.x >= ui) + (v2.x >= ui) + (v3.x >= ui);
    r1 += (v0.y >= ui) + (v1.y >= ui) + (v2.y >= ui) + (v3.y >= ui);
    r2 += (v0.z >= ui) + (v1.z >= ui) + (v2.z >= ui) + (v3.z >= ui);
    r3 += (v0.w >= ui) + (v1.w >= ui) + (v2.w >= ui) + (v3.w >= ui);
  }
  // Boundary chunk: full original predicate over this wave's 64 candidates
  for (int j = wb; j < wb + 64; ++j) {
    float vj = ub[j];
    r0 += (vj > ui) || (vj == ui && j < i);
  }
  // Phase B: j >= wb+64  ->  count (u[j] > ui)
  for (int j = wb + 64; j < NS; j += 16) {
    float4 v0 = *(const float4*)&ub[j];
    float4 v1 = *(const float4*)&ub[j + 4];
    float4 v2 = *(const float4*)&ub[j + 8];
    float4 v3 = *(const float4*)&ub[j + 12];
    r0 += (v0.x > ui) + (v1.x > ui) + (v2.x > ui) + (v3.x > ui);
    r1 += (v0.y > ui) + (v1.y > ui) + (v2.y > ui) + (v3.y > ui);
    r2 += (v0.z > ui) + (v1.z > ui) + (v2.z > ui) + (v3.z > ui);
    r3 += (v0.w > ui) + (v1.w > ui) + (v2.w > ui) + (v3.w > ui);
  }
  int rank = (r0 + r1) + (r2 + r3);
  if (rank < NU) {
    pts_out[((size_t)b * NP + rank) * 2 + 0] = rp[((size_t)b * NS + i) * 2 + 0];
    pts_out[((size_t)b * NP + rank) * 2 + 1] = rp[((size_t)b * NS + i) * 2 + 1];
  }
}

// ---------------------------------------------------------------------------
// K3: gather with inline per-point bilinear metadata (k_prep fused; each
// (channel,batch,quarter) block recomputes its 1024 points' metadata —
// identical FP expressions, deterministic). Natural point order; coalesced
// pts reads and featsT stores; scattered plane taps are compulsory traffic.
// Output transposed: featsT[c][b*NP + s].
// ---------------------------------------------------------------------------
__global__ __launch_bounds__(256) void k_gather4(
    const float* __restrict__ fine, const float* __restrict__ coarse,
    const float* __restrict__ pts, float* __restrict__ featsT) {
  int c = blockIdx.x % CIN;
  int rem = blockIdx.x / CIN;
  int b = rem & (BATCH - 1);
  int part = rem >> 2;
  const float* plane = (c < CF_CH)
                           ? fine + ((size_t)b * CF_CH + c) * NPLANE
                           : coarse + ((size_t)b * CC_CH + (c - CF_CH)) * NPLANE;
  const float* pb = pts + (size_t)b * NP * 2;
  float* outrow = featsT + (size_t)c * M_TOT + (size_t)b * NP;
  int s0 = part * (NP / GCH_SPLIT);
#pragma unroll
  for (int q = 0; q < NP / GCH_SPLIT / 256; ++q) {
    int s = s0 + q * 256 + (int)threadIdx.x;
    float px = pb[2 * s + 0];
    float py = pb[2 * s + 1];
    float x = px * 512.0f - 0.5f;
    float y = py * 512.0f - 0.5f;
    float x0f = floorf(x), y0f = floorf(y);
    float wx = x - x0f, wy = y - y0f;
    int x0 = (int)x0f, y0 = (int)y0f;
    bool vx0 = (unsigned)x0 < (unsigned)HW;
    bool vx1 = (unsigned)(x0 + 1) < (unsigned)HW;
    bool vy0 = (unsigned)y0 < (unsigned)HW;
    bool vy1 = (unsigned)(y0 + 1) < (unsigned)HW;
    const float* bp = plane + (y0 * HW + x0);
    float t00 = 0.0f, t10 = 0.0f, t01 = 0.0f, t11 = 0.0f;
    if (vx0 && vy0) t00 = bp[0] * ((1.0f - wx) * (1.0f - wy));
    if (vx1 && vy0) t10 = bp[1] * (wx * (1.0f - wy));
    if (vx0 && vy1) t01 = bp[HW] * ((1.0f - wx) * wy);
    if (vx1 && vy1) t11 = bp[HW + 1] * (wx * wy);
    outrow[s] = ((t00 + t10) + t01) + t11;
  }
}

// ---------------------------------------------------------------------------
// K4: GEMM layer 1 from transposed A (At[k][m]), C[M][256] row-major.
// 64x64 tile, BK=32, 256 threads, 4x4 acc.
// ---------------------------------------------------------------------------
__global__ __launch_bounds__(256) void k_gemm1_At(const float* __restrict__ At,
                                                  const float* __restrict__ W,
                                                  const float* __restrict__ bias,
                                                  float* __restrict__ C) {
  __shared__ __align__(16) float As[32][68];
  __shared__ __align__(16) float Bs[32][68];
  const int bx = blockIdx.x & 3;   // N tile
  const int by = blockIdx.x >> 2;  // M tile
  const int tid = threadIdx.x;
  const int tn = tid & 15, tm = tid >> 4;
  const int m_base = by * 64, n_base = bx * 64;
  float acc[4][4] = {};
  for (int k0 = 0; k0 < CIN; k0 += 32) {
#pragma unroll
    for (int r = 0; r < 2; ++r) {
      int t = tid + r * 256;
      int kk = t >> 4, mg = (t & 15) * 4;
      *(float4*)&As[kk][mg] =
          *(const float4*)&At[(size_t)(k0 + kk) * M_TOT + m_base + mg];
      int row = t >> 3, cg = (t & 7) * 4;
      float4 vw = *(const float4*)&W[(size_t)(n_base + row) * CIN + k0 + cg];
      Bs[cg + 0][row] = vw.x;
      Bs[cg + 1][row] = vw.y;
      Bs[cg + 2][row] = vw.z;
      Bs[cg + 3][row] = vw.w;
    }
    __syncthreads();
#pragma unroll
    for (int kk = 0; kk < 32; ++kk) {
      float4 a4 = *(const float4*)&As[kk][tm * 4];
      float4 b4 = *(const float4*)&Bs[kk][tn * 4];
      float av[4] = {a4.x, a4.y, a4.z, a4.w};
      float bw[4] = {b4.x, b4.y, b4.z, b4.w};
#pragma unroll
      for (int i = 0; i < 4; ++i)
#pragma unroll
        for (int j = 0; j < 4; ++j) acc[i][j] = fmaf(av[i], bw[j], acc[i][j]);
    }
    __syncthreads();
  }
  float bs[4];
#pragma unroll
  for (int j = 0; j < 4; ++j) bs[j] = bias[n_base + tn * 4 + j];
#pragma unroll
  for (int i = 0; i < 4; ++i) {
    float4 o;
    o.x = fmaxf(acc[i][0] + bs[0], 0.0f);
    o.y = fmaxf(acc[i][1] + bs[1], 0.0f);
    o.z = fmaxf(acc[i][2] + bs[2], 0.0f);
    o.w = fmaxf(acc[i][3] + bs[3], 0.0f);
    *(float4*)&C[(size_t)(m_base + tm * 4 + i) * HID + n_base + tn * 4] = o;
  }
}

// ---------------------------------------------------------------------------
// K5: GEMM layer 2 (row-major A).
// ---------------------------------------------------------------------------
template <int K>
__global__ __launch_bounds__(256) void k_gemm_relu(const float* __restrict__ A,
                                                   const float* __restrict__ W,
                                                   const float* __restrict__ bias,
                                                   float* __restrict__ C) {
  __shared__ __align__(16) float As[32][68];
  __shared__ __align__(16) float Bs[32][68];
  const int bx = blockIdx.x & 3;
  const int by = blockIdx.x >> 2;
  const int tid = threadIdx.x;
  const int tn = tid & 15, tm = tid >> 4;
  const int m_base = by * 64, n_base = bx * 64;
  float acc[4][4] = {};
  for (int k0 = 0; k0 < K; k0 += 32) {
#pragma unroll
    for (int r = 0; r < 2; ++r) {
      int t = tid + r * 256;
      int row = t >> 3, cg = (t & 7) * 4;
      float4 va = *(const float4*)&A[(size_t)(m_base + row) * K + k0 + cg];
      As[cg + 0][row] = va.x;
      As[cg + 1][row] = va.y;
      As[cg + 2][row] = va.z;
      As[cg + 3][row] = va.w;
      float4 vw = *(const float4*)&W[(size_t)(n_base + row) * K + k0 + cg];
      Bs[cg + 0][row] = vw.x;
      Bs[cg + 1][row] = vw.y;
      Bs[cg + 2][row] = vw.z;
      Bs[cg + 3][row] = vw.w;
    }
    __syncthreads();
#pragma unroll
    for (int kk = 0; kk < 32; ++kk) {
      float4 a4 = *(const float4*)&As[kk][tm * 4];
      float4 b4 = *(const float4*)&Bs[kk][tn * 4];
      float av[4] = {a4.x, a4.y, a4.z, a4.w};
      float bw[4] = {b4.x, b4.y, b4.z, b4.w};
#pragma unroll
      for (int i = 0; i < 4; ++i)
#pragma unroll
        for (int j = 0; j < 4; ++j) acc[i][j] = fmaf(av[i], bw[j], acc[i][j]);
    }
    __syncthreads();
  }
  float bs[4];
#pragma unroll
  for (int j = 0; j < 4; ++j) bs[j] = bias[n_base + tn * 4 + j];
#pragma unroll
  for (int i = 0; i < 4; ++i) {
    float4 o;
    o.x = fmaxf(acc[i][0] + bs[0], 0.0f);
    o.y = fmaxf(acc[i][1] + bs[1], 0.0f);
    o.z = fmaxf(acc[i][2] + bs[2], 0.0f);
    o.w = fmaxf(acc[i][3] + bs[3], 0.0f);
    *(float4*)&C[(size_t)(m_base + tm * 4 + i) * HID + n_base + tn * 4] = o;
  }
}

// ---------------------------------------------------------------------------
// K6: final layer, 4 outputs per point, shuffle reduce.
// ---------------------------------------------------------------------------
__global__ __launch_bounds__(256) void k_out(const float* __restrict__ h,
                                             const float* __restrict__ W3,
                                             const float* __restrict__ b3,
                                             float* __restrict__ out) {
  int gp = blockIdx.x * 4 + (threadIdx.x >> 6);
  int lane = threadIdx.x & 63;
  const float* hr = h + (size_t)gp * HID;
  float4 hv = *(const float4*)&hr[lane * 4];
  float s[4];
#pragma unroll
  for (int o = 0; o < 4; ++o) {
    float4 w = *(const float4*)&W3[o * HID + lane * 4];
    s[o] = hv.x * w.x + hv.y * w.y + hv.z * w.z + hv.w * w.w;
  }
#pragma unroll
  for (int off = 32; off; off >>= 1)
#pragma unroll
    for (int o = 0; o < 4; ++o) s[o] += __shfl_xor(s[o], off, 64);
  if (lane == 0) {
    int b = gp / NP, n = gp % NP;
#pragma unroll
    for (int o = 0; o < 4; ++o)
      out[((size_t)b * OUTC + o) * NP + n] = s[o] + b3[o];
  }
}

extern "C" void kernel_launch(void* const* d_in, const int* in_sizes, int n_in,
                              void* d_out, int out_size, void* d_ws, size_t ws_size,
                              hipStream_t stream) {
  const float* fine = (const float*)d_in[0];
  const float* coarse = (const float*)d_in[1];
  const float* logits = (const float*)d_in[2];
  const float* rand_points = (const float*)d_in[3];
  const float* rand_extra = (const float*)d_in[4];
  const float* W1 = (const float*)d_in[5];
  const float* b1 = (const float*)d_in[6];
  const float* W2 = (const float*)d_in[7];
  const float* b2 = (const float*)d_in[8];
  const float* W3 = (const float*)d_in[9];
  const float* b3 = (const float*)d_in[10];
  float* out = (float*)d_out;

  float* out_logits = out;
  float* out_points = out + (size_t)BATCH * OUTC * NP;

  // ws layout (bytes): u | featsT | h1 | h2
  char* ws = (char*)d_ws;
  float* u = (float*)(ws + 0);              // 196608
  float* featsT = (float*)(ws + 196608);    // 12582912
  float* h1 = (float*)(ws + 12779520);      // 16777216
  float* h2 = (float*)(ws + 29556736);      // 16777216

  k_uncert_extra<<<(BATCH * NS + BATCH * NR + 255) / 256, 256, 0, stream>>>(
      logits, rand_points, rand_extra, u, out_points);
  k_select<<<BATCH * (NS / 256), 256, 0, stream>>>(u, rand_points, out_points);
  k_gather4<<<CIN * BATCH * GCH_SPLIT, 256, 0, stream>>>(fine, coarse,
                                                         out_points, featsT);
  k_gemm1_At<<<(M_TOT / 64) * 4, 256, 0, stream>>>(featsT, W1, b1, h1);
  k_gemm_relu<HID><<<(M_TOT / 64) * 4, 256, 0, stream>>>(h1, W2, b2, h2);
  k_out<<<M_TOT / 4, 256, 0, stream>>>(h2, W3, b3, out_logits);
}

// Round 8
// 369.099 us; speedup vs baseline: 1.0971x; 1.0971x over previous
//
#include <hip/hip_runtime.h>
#include <math.h>

// Problem constants (from reference)
#define BATCH 4
#define HW 512
#define NPLANE (512 * 512)
#define NS 12288      // oversampled points per batch
#define NU 3072       // top-k uncertain selected
#define NR 1024       // random extra points
#define NP 4096       // total selected points per batch
#define CF_CH 64
#define CC_CH 128
#define CIN 192
#define HID 256
#define OUTC 4
#define M_TOT (BATCH * NP)  // 16384
#define GCH_SPLIT 4         // point-chunks per (batch, channel) in gather
#define SHALF 6144          // candidates staged in LDS (rest read via global/L2)

// ---------------------------------------------------------------------------
// Bit-exact replication of XLA:CPU's vectorized f32 expf (Cephes polynomial),
// strict per-op f32 rounding, no FMA. DO NOT TOUCH — top-k order depends on it.
// ---------------------------------------------------------------------------
__device__ __forceinline__ float xla_expf(float xin) {
  float x = fminf(fmaxf(xin, -88.3762626647949f), 88.3762626647950f);
  float fx = floorf(__fadd_rn(__fmul_rn(x, 1.44269504088896341f), 0.5f));
  float tmp = __fmul_rn(0.693359375f, fx);
  float z = __fmul_rn(-2.12194440e-4f, fx);
  x = __fsub_rn(__fsub_rn(x, tmp), z);
  float y = __fadd_rn(__fmul_rn(x, 1.9875691500E-4f), 1.3981999507E-3f);
  y = __fadd_rn(__fmul_rn(y, x), 8.3334519073E-3f);
  y = __fadd_rn(__fmul_rn(y, x), 4.1665795894E-2f);
  y = __fadd_rn(__fmul_rn(y, x), 1.6666665459E-1f);
  y = __fadd_rn(__fmul_rn(y, x), 5.0000001201E-1f);
  z = __fmul_rn(x, x);
  y = __fadd_rn(__fmul_rn(y, z), x);
  y = __fadd_rn(y, 1.0f);
  int n = (int)fx;
  float p2n = __int_as_float((n + 127) << 23);
  return __fmul_rn(y, p2n);
}

// ---------------------------------------------------------------------------
// K1: uncertainty at oversampled points — bit-replicates reference f32 chain.
// (R2/R6-verified.)
// ---------------------------------------------------------------------------
__global__ void k_uncert(const float* __restrict__ logits,
                         const float* __restrict__ rp,
                         float* __restrict__ u) {
  int gid = blockIdx.x * 256 + threadIdx.x;
  if (gid >= BATCH * NS) return;
  int b = gid / NS;
  float px = rp[(size_t)gid * 2 + 0];
  float py = rp[(size_t)gid * 2 + 1];
  const float* plane = logits + (size_t)b * OUTC * NPLANE;  // channel 0

  float x = __fsub_rn(__fmul_rn(px, 512.0f), 0.5f);
  float y = __fsub_rn(__fmul_rn(py, 512.0f), 0.5f);
  float x0f = floorf(x), y0f = floorf(y);
  float wx = __fsub_rn(x, x0f);
  float wy = __fsub_rn(y, y0f);
  int x0 = (int)x0f, y0 = (int)y0f;
  int x1 = x0 + 1, y1 = y0 + 1;
  bool vx0 = (x0 >= 0) & (x0 < HW);
  bool vx1 = (x1 >= 0) & (x1 < HW);
  bool vy0 = (y0 >= 0) & (y0 < HW);
  bool vy1 = (y1 >= 0) & (y1 < HW);
  float g00 = (vx0 && vy0) ? plane[y0 * HW + x0] : 0.0f;
  float g10 = (vx1 && vy0) ? plane[y0 * HW + x1] : 0.0f;
  float g01 = (vx0 && vy1) ? plane[y1 * HW + x0] : 0.0f;
  float g11 = (vx1 && vy1) ? plane[y1 * HW + x1] : 0.0f;
  float omx = __fsub_rn(1.0f, wx);
  float omy = __fsub_rn(1.0f, wy);
  float w00 = __fmul_rn(omx, omy);
  float w10 = __fmul_rn(wx, omy);
  float w01 = __fmul_rn(omx, wy);
  float w11 = __fmul_rn(wx, wy);
  float s = __fadd_rn(
      __fadd_rn(__fadd_rn(__fmul_rn(g00, w00), __fmul_rn(g10, w10)),
                __fmul_rn(g01, w01)),
      __fmul_rn(g11, w11));
  float e = xla_expf(-s);
  float sig = __fdiv_rn(1.0f, __fadd_rn(1.0f, e));
  float t = __fmul_rn(fabsf(__fsub_rn(sig, 0.5f)), 2.0f);
  u[gid] = __fsub_rn(1.0f, t);
}

// ---------------------------------------------------------------------------
// K2: exact stable top-k via ranking — R6-verified split-predicate compares
// (bit-identical counting), hybrid candidate source: j < SHALF read from an
// LDS stage, j >= SHALF read from global (L2-resident). LDS and VMEM pipes
// run in parallel, halving the serialized ds_read stream that bounded R6.
//   j <  wave_base       : (u_j>u_i)||(u_j==u_i && j<i)  ==  (u_j >= u_i)
//   j in [wb, wb+64)     : full original predicate (includes j==i -> 0)
//   j >= wave_base + 64  : ==  (u_j > u_i)
// All loop bounds are multiples of 64 so no chunk straddles SHALF.
// ---------------------------------------------------------------------------
__global__ __launch_bounds__(256) void k_select(const float* __restrict__ u,
                                                const float* __restrict__ rp,
                                                float* __restrict__ pts_out) {
  __shared__ __align__(16) float su[SHALF];
  int b = blockIdx.x / (NS / 256);
  int blk = blockIdx.x % (NS / 256);
  const float* __restrict__ ub = u + (size_t)b * NS;
  for (int t = threadIdx.x; t < SHALF / 4; t += 256)
    ((float4*)su)[t] = ((const float4*)ub)[t];
  __syncthreads();
  int i = blk * 256 + (int)threadIdx.x;
  int wb = i & ~63;  // wave-uniform (blk*256 is 64-aligned)
  float ui = ub[i];  // same bits as su[i] when i < SHALF
  int r0 = 0, r1 = 0, r2 = 0, r3 = 0;
  // ---- Phase A: j < wb -> count (u[j] >= ui) ----
  int aLds = min(wb, SHALF);
  for (int j = 0; j < aLds; j += 8) {
    float4 v = *(const float4*)&su[j];
    float4 w = *(const float4*)&su[j + 4];
    r0 += (v.x >= ui) + (w.x >= ui);
    r1 += (v.y >= ui) + (w.y >= ui);
    r2 += (v.z >= ui) + (w.z >= ui);
    r3 += (v.w >= ui) + (w.w >= ui);
  }
  for (int j = SHALF; j < wb; j += 8) {  // only if wb > SHALF
    float4 v = *(const float4*)&ub[j];
    float4 w = *(const float4*)&ub[j + 4];
    r0 += (v.x >= ui) + (w.x >= ui);
    r1 += (v.y >= ui) + (w.y >= ui);
    r2 += (v.z >= ui) + (w.z >= ui);
    r3 += (v.w >= ui) + (w.w >= ui);
  }
  // ---- Boundary chunk [wb, wb+64): full original predicate ----
  if (wb < SHALF) {
    for (int j = wb; j < wb + 64; ++j) {
      float vj = su[j];
      r0 += (vj > ui) || (vj == ui && j < i);
    }
  } else {
    for (int j = wb; j < wb + 64; ++j) {
      float vj = ub[j];
      r0 += (vj > ui) || (vj == ui && j < i);
    }
  }
  // ---- Phase B: j >= wb+64 -> count (u[j] > ui) ----
  for (int j = wb + 64; j < SHALF; j += 8) {  // only if wb+64 < SHALF
    float4 v = *(const float4*)&su[j];
    float4 w = *(const float4*)&su[j + 4];
    r0 += (v.x > ui) + (w.x > ui);
    r1 += (v.y > ui) + (w.y > ui);
    r2 += (v.z > ui) + (w.z > ui);
    r3 += (v.w > ui) + (w.w > ui);
  }
  int bGlo = max(wb + 64, SHALF);
  for (int j = bGlo; j < NS; j += 8) {
    float4 v = *(const float4*)&ub[j];
    float4 w = *(const float4*)&ub[j + 4];
    r0 += (v.x > ui) + (w.x > ui);
    r1 += (v.y > ui) + (w.y > ui);
    r2 += (v.z > ui) + (w.z > ui);
    r3 += (v.w > ui) + (w.w > ui);
  }
  int rank = (r0 + r1) + (r2 + r3);
  if (rank < NU) {
    pts_out[((size_t)b * NP + rank) * 2 + 0] = rp[((size_t)b * NS + i) * 2 + 0];
    pts_out[((size_t)b * NP + rank) * 2 + 1] = rp[((size_t)b * NS + i) * 2 + 1];
  }
}

// K2b: append the random-extra points (R2/R6-verified).
__global__ void k_extra(const float* __restrict__ re, float* __restrict__ pts_out) {
  int gid = blockIdx.x * 256 + threadIdx.x;
  if (gid >= BATCH * NR) return;
  int b = gid / NR, j = gid % NR;
  pts_out[((size_t)b * NP + NU + j) * 2 + 0] = re[(size_t)gid * 2 + 0];
  pts_out[((size_t)b * NP + NU + j) * 2 + 1] = re[(size_t)gid * 2 + 1];
}

// ---------------------------------------------------------------------------
// K3a: per-point bilinear metadata (R6-verified).
// ---------------------------------------------------------------------------
__global__ void k_prep(const float* __restrict__ pts, int2* __restrict__ m2,
                       float4* __restrict__ wts) {
  int g = blockIdx.x * 256 + threadIdx.x;
  if (g >= M_TOT) return;
  float px = pts[(size_t)g * 2 + 0];
  float py = pts[(size_t)g * 2 + 1];
  float x = px * 512.0f - 0.5f;
  float y = py * 512.0f - 0.5f;
  float x0f = floorf(x), y0f = floorf(y);
  float wx = x - x0f, wy = y - y0f;
  int x0 = (int)x0f, y0 = (int)y0f;
  bool vx0 = (unsigned)x0 < (unsigned)HW;
  bool vx1 = (unsigned)(x0 + 1) < (unsigned)HW;
  bool vy0 = (unsigned)y0 < (unsigned)HW;
  bool vy1 = (unsigned)(y0 + 1) < (unsigned)HW;
  int vm = (int)(vx0 && vy0) | ((int)(vx1 && vy0) << 1) |
           ((int)(vx0 && vy1) << 2) | ((int)(vx1 && vy1) << 3);
  m2[g] = make_int2(y0 * HW + x0, vm);
  wts[g] = make_float4((1.0f - wx) * (1.0f - wy), wx * (1.0f - wy),
                       (1.0f - wx) * wy, wx * wy);
}

// ---------------------------------------------------------------------------
// K3b: gather (R6-verified). One block per (channel, batch, quarter);
// GCH_SPLIT=4 -> 3072 blocks, 4 points/thread fully unrolled.
// Output transposed: featsT[c][b*NP + s].
// ---------------------------------------------------------------------------
__global__ __launch_bounds__(256) void k_gather3(
    const float* __restrict__ fine, const float* __restrict__ coarse,
    const int2* __restrict__ m2, const float4* __restrict__ wts,
    float* __restrict__ featsT) {
  int c = blockIdx.x % CIN;
  int rem = blockIdx.x / CIN;
  int b = rem & (BATCH - 1);
  int part = rem >> 2;
  const float* plane = (c < CF_CH)
                           ? fine + ((size_t)b * CF_CH + c) * NPLANE
                           : coarse + ((size_t)b * CC_CH + (c - CF_CH)) * NPLANE;
  const int2* m2b = m2 + (size_t)b * NP;
  const float4* wtsb = wts + (size_t)b * NP;
  float* outrow = featsT + (size_t)c * M_TOT + (size_t)b * NP;
  int s0 = part * (NP / GCH_SPLIT);
#pragma unroll
  for (int q = 0; q < NP / GCH_SPLIT / 256; ++q) {
    int s = s0 + q * 256 + (int)threadIdx.x;
    int2 mm = m2b[s];
    float4 w = wtsb[s];
    const float* bp = plane + mm.x;
    float t00 = 0.0f, t10 = 0.0f, t01 = 0.0f, t11 = 0.0f;
    if (mm.y & 1) t00 = bp[0] * w.x;
    if (mm.y & 2) t10 = bp[1] * w.y;
    if (mm.y & 4) t01 = bp[HW] * w.z;
    if (mm.y & 8) t11 = bp[HW + 1] * w.w;
    outrow[s] = ((t00 + t10) + t01) + t11;
  }
}

// ---------------------------------------------------------------------------
// K4: GEMM layer 1 from transposed A (At[k][m]), C[M][256] row-major.
// 64x64 tile, BK=32, 256 threads, 4x4 acc. (R6-verified.)
// ---------------------------------------------------------------------------
__global__ __launch_bounds__(256) void k_gemm1_At(const float* __restrict__ At,
                                                  const float* __restrict__ W,
                                                  const float* __restrict__ bias,
                                                  float* __restrict__ C) {
  __shared__ __align__(16) float As[32][68];
  __shared__ __align__(16) float Bs[32][68];
  const int bx = blockIdx.x & 3;   // N tile
  const int by = blockIdx.x >> 2;  // M tile
  const int tid = threadIdx.x;
  const int tn = tid & 15, tm = tid >> 4;
  const int m_base = by * 64, n_base = bx * 64;
  float acc[4][4] = {};
  for (int k0 = 0; k0 < CIN; k0 += 32) {
#pragma unroll
    for (int r = 0; r < 2; ++r) {
      int t = tid + r * 256;
      int kk = t >> 4, mg = (t & 15) * 4;
      *(float4*)&As[kk][mg] =
          *(const float4*)&At[(size_t)(k0 + kk) * M_TOT + m_base + mg];
      int row = t >> 3, cg = (t & 7) * 4;
      float4 vw = *(const float4*)&W[(size_t)(n_base + row) * CIN + k0 + cg];
      Bs[cg + 0][row] = vw.x;
      Bs[cg + 1][row] = vw.y;
      Bs[cg + 2][row] = vw.z;
      Bs[cg + 3][row] = vw.w;
    }
    __syncthreads();
#pragma unroll
    for (int kk = 0; kk < 32; ++kk) {
      float4 a4 = *(const float4*)&As[kk][tm * 4];
      float4 b4 = *(const float4*)&Bs[kk][tn * 4];
      float av[4] = {a4.x, a4.y, a4.z, a4.w};
      float bw[4] = {b4.x, b4.y, b4.z, b4.w};
#pragma unroll
      for (int i = 0; i < 4; ++i)
#pragma unroll
        for (int j = 0; j < 4; ++j) acc[i][j] = fmaf(av[i], bw[j], acc[i][j]);
    }
    __syncthreads();
  }
  float bs[4];
#pragma unroll
  for (int j = 0; j < 4; ++j) bs[j] = bias[n_base + tn * 4 + j];
#pragma unroll
  for (int i = 0; i < 4; ++i) {
    float4 o;
    o.x = fmaxf(acc[i][0] + bs[0], 0.0f);
    o.y = fmaxf(acc[i][1] + bs[1], 0.0f);
    o.z = fmaxf(acc[i][2] + bs[2], 0.0f);
    o.w = fmaxf(acc[i][3] + bs[3], 0.0f);
    *(float4*)&C[(size_t)(m_base + tm * 4 + i) * HID + n_base + tn * 4] = o;
  }
}

// ---------------------------------------------------------------------------
// K5: GEMM layer 2 (row-major A). (R6-verified.)
// ---------------------------------------------------------------------------
template <int K>
__global__ __launch_bounds__(256) void k_gemm_relu(const float* __restrict__ A,
                                                   const float* __restrict__ W,
                                                   const float* __restrict__ bias,
                                                   float* __restrict__ C) {
  __shared__ __align__(16) float As[32][68];
  __shared__ __align__(16) float Bs[32][68];
  const int bx = blockIdx.x & 3;
  const int by = blockIdx.x >> 2;
  const int tid = threadIdx.x;
  const int tn = tid & 15, tm = tid >> 4;
  const int m_base = by * 64, n_base = bx * 64;
  float acc[4][4] = {};
  for (int k0 = 0; k0 < K; k0 += 32) {
#pragma unroll
    for (int r = 0; r < 2; ++r) {
      int t = tid + r * 256;
      int row = t >> 3, cg = (t & 7) * 4;
      float4 va = *(const float4*)&A[(size_t)(m_base + row) * K + k0 + cg];
      As[cg + 0][row] = va.x;
      As[cg + 1][row] = va.y;
      As[cg + 2][row] = va.z;
      As[cg + 3][row] = va.w;
      float4 vw = *(const float4*)&W[(size_t)(n_base + row) * K + k0 + cg];
      Bs[cg + 0][row] = vw.x;
      Bs[cg + 1][row] = vw.y;
      Bs[cg + 2][row] = vw.z;
      Bs[cg + 3][row] = vw.w;
    }
    __syncthreads();
#pragma unroll
    for (int kk = 0; kk < 32; ++kk) {
      float4 a4 = *(const float4*)&As[kk][tm * 4];
      float4 b4 = *(const float4*)&Bs[kk][tn * 4];
      float av[4] = {a4.x, a4.y, a4.z, a4.w};
      float bw[4] = {b4.x, b4.y, b4.z, b4.w};
#pragma unroll
      for (int i = 0; i < 4; ++i)
#pragma unroll
        for (int j = 0; j < 4; ++j) acc[i][j] = fmaf(av[i], bw[j], acc[i][j]);
    }
    __syncthreads();
  }
  float bs[4];
#pragma unroll
  for (int j = 0; j < 4; ++j) bs[j] = bias[n_base + tn * 4 + j];
#pragma unroll
  for (int i = 0; i < 4; ++i) {
    float4 o;
    o.x = fmaxf(acc[i][0] + bs[0], 0.0f);
    o.y = fmaxf(acc[i][1] + bs[1], 0.0f);
    o.z = fmaxf(acc[i][2] + bs[2], 0.0f);
    o.w = fmaxf(acc[i][3] + bs[3], 0.0f);
    *(float4*)&C[(size_t)(m_base + tm * 4 + i) * HID + n_base + tn * 4] = o;
  }
}

// ---------------------------------------------------------------------------
// K6: final layer, 4 outputs per point, shuffle reduce. (R6-verified.)
// ---------------------------------------------------------------------------
__global__ __launch_bounds__(256) void k_out(const float* __restrict__ h,
                                             const float* __restrict__ W3,
                                             const float* __restrict__ b3,
                                             float* __restrict__ out) {
  int gp = blockIdx.x * 4 + (threadIdx.x >> 6);
  int lane = threadIdx.x & 63;
  const float* hr = h + (size_t)gp * HID;
  float4 hv = *(const float4*)&hr[lane * 4];
  float s[4];
#pragma unroll
  for (int o = 0; o < 4; ++o) {
    float4 w = *(const float4*)&W3[o * HID + lane * 4];
    s[o] = hv.x * w.x + hv.y * w.y + hv.z * w.z + hv.w * w.w;
  }
#pragma unroll
  for (int off = 32; off; off >>= 1)
#pragma unroll
    for (int o = 0; o < 4; ++o) s[o] += __shfl_xor(s[o], off, 64);
  if (lane == 0) {
    int b = gp / NP, n = gp % NP;
#pragma unroll
    for (int o = 0; o < 4; ++o)
      out[((size_t)b * OUTC + o) * NP + n] = s[o] + b3[o];
  }
}

extern "C" void kernel_launch(void* const* d_in, const int* in_sizes, int n_in,
                              void* d_out, int out_size, void* d_ws, size_t ws_size,
                              hipStream_t stream) {
  const float* fine = (const float*)d_in[0];
  const float* coarse = (const float*)d_in[1];
  const float* logits = (const float*)d_in[2];
  const float* rand_points = (const float*)d_in[3];
  const float* rand_extra = (const float*)d_in[4];
  const float* W1 = (const float*)d_in[5];
  const float* b1 = (const float*)d_in[6];
  const float* W2 = (const float*)d_in[7];
  const float* b2 = (const float*)d_in[8];
  const float* W3 = (const float*)d_in[9];
  const float* b3 = (const float*)d_in[10];
  float* out = (float*)d_out;

  float* out_logits = out;
  float* out_points = out + (size_t)BATCH * OUTC * NP;

  // ws layout (bytes): u | m2 | wts | featsT | h1 | h2
  char* ws = (char*)d_ws;
  float* u = (float*)(ws + 0);              // 196608
  int2* m2 = (int2*)(ws + 196608);          // 131072
  float4* wts = (float4*)(ws + 327680);     // 262144
  float* featsT = (float*)(ws + 589824);    // 12582912
  float* h1 = (float*)(ws + 13172736);      // 16777216
  float* h2 = (float*)(ws + 29949952);      // 16777216

  k_uncert<<<(BATCH * NS + 255) / 256, 256, 0, stream>>>(logits, rand_points, u);
  k_select<<<BATCH * (NS / 256), 256, 0, stream>>>(u, rand_points, out_points);
  k_extra<<<(BATCH * NR + 255) / 256, 256, 0, stream>>>(rand_extra, out_points);
  k_prep<<<(M_TOT + 255) / 256, 256, 0, stream>>>(out_points, m2, wts);
  k_gather3<<<CIN * BATCH * GCH_SPLIT, 256, 0, stream>>>(fine, coarse, m2, wts,
                                                         featsT);
  k_gemm1_At<<<(M_TOT / 64) * 4, 256, 0, stream>>>(featsT, W1, b1, h1);
  k_gemm_relu<HID><<<(M_TOT / 64) * 4, 256, 0, stream>>>(h1, W2, b2, h2);
  k_out<<<M_TOT / 4, 256, 0, stream>>>(h2, W3, b3, out_logits);
}

// Round 9
// 305.965 us; speedup vs baseline: 1.3235x; 1.2063x over previous
//
#include <hip/hip_runtime.h>
#include <math.h>

// Problem constants (from reference)
#define BATCH 4
#define HW 512
#define NPLANE (512 * 512)
#define NS 12288      // oversampled points per batch
#define NU 3072       // top-k uncertain selected
#define NR 1024       // random extra points
#define NP 4096       // total selected points per batch
#define CF_CH 64
#define CC_CH 128
#define CIN 192
#define HID 256
#define OUTC 4
#define M_TOT (BATCH * NP)  // 16384
#define GCH_SPLIT 4         // point-chunks per (batch, channel) in gather

// ---------------------------------------------------------------------------
// Bit-exact replication of XLA:CPU's vectorized f32 expf (Cephes polynomial),
// strict per-op f32 rounding, no FMA. DO NOT TOUCH — top-k order depends on it.
// ---------------------------------------------------------------------------
__device__ __forceinline__ float xla_expf(float xin) {
  float x = fminf(fmaxf(xin, -88.3762626647949f), 88.3762626647950f);
  float fx = floorf(__fadd_rn(__fmul_rn(x, 1.44269504088896341f), 0.5f));
  float tmp = __fmul_rn(0.693359375f, fx);
  float z = __fmul_rn(-2.12194440e-4f, fx);
  x = __fsub_rn(__fsub_rn(x, tmp), z);
  float y = __fadd_rn(__fmul_rn(x, 1.9875691500E-4f), 1.3981999507E-3f);
  y = __fadd_rn(__fmul_rn(y, x), 8.3334519073E-3f);
  y = __fadd_rn(__fmul_rn(y, x), 4.1665795894E-2f);
  y = __fadd_rn(__fmul_rn(y, x), 1.6666665459E-1f);
  y = __fadd_rn(__fmul_rn(y, x), 5.0000001201E-1f);
  z = __fmul_rn(x, x);
  y = __fadd_rn(__fmul_rn(y, z), x);
  y = __fadd_rn(y, 1.0f);
  int n = (int)fx;
  float p2n = __int_as_float((n + 127) << 23);
  return __fmul_rn(y, p2n);
}

// ---------------------------------------------------------------------------
// K1: uncertainty at oversampled points — bit-replicates reference f32 chain.
// (R2/R6-verified, byte-identical.)
// ---------------------------------------------------------------------------
__global__ void k_uncert(const float* __restrict__ logits,
                         const float* __restrict__ rp,
                         float* __restrict__ u) {
  int gid = blockIdx.x * 256 + threadIdx.x;
  if (gid >= BATCH * NS) return;
  int b = gid / NS;
  float px = rp[(size_t)gid * 2 + 0];
  float py = rp[(size_t)gid * 2 + 1];
  const float* plane = logits + (size_t)b * OUTC * NPLANE;  // channel 0

  float x = __fsub_rn(__fmul_rn(px, 512.0f), 0.5f);
  float y = __fsub_rn(__fmul_rn(py, 512.0f), 0.5f);
  float x0f = floorf(x), y0f = floorf(y);
  float wx = __fsub_rn(x, x0f);
  float wy = __fsub_rn(y, y0f);
  int x0 = (int)x0f, y0 = (int)y0f;
  int x1 = x0 + 1, y1 = y0 + 1;
  bool vx0 = (x0 >= 0) & (x0 < HW);
  bool vx1 = (x1 >= 0) & (x1 < HW);
  bool vy0 = (y0 >= 0) & (y0 < HW);
  bool vy1 = (y1 >= 0) & (y1 < HW);
  float g00 = (vx0 && vy0) ? plane[y0 * HW + x0] : 0.0f;
  float g10 = (vx1 && vy0) ? plane[y0 * HW + x1] : 0.0f;
  float g01 = (vx0 && vy1) ? plane[y1 * HW + x0] : 0.0f;
  float g11 = (vx1 && vy1) ? plane[y1 * HW + x1] : 0.0f;
  float omx = __fsub_rn(1.0f, wx);
  float omy = __fsub_rn(1.0f, wy);
  float w00 = __fmul_rn(omx, omy);
  float w10 = __fmul_rn(wx, omy);
  float w01 = __fmul_rn(omx, wy);
  float w11 = __fmul_rn(wx, wy);
  float s = __fadd_rn(
      __fadd_rn(__fadd_rn(__fmul_rn(g00, w00), __fmul_rn(g10, w10)),
                __fmul_rn(g01, w01)),
      __fmul_rn(g11, w11));
  float e = xla_expf(-s);
  float sig = __fdiv_rn(1.0f, __fadd_rn(1.0f, e));
  float t = __fmul_rn(fabsf(__fsub_rn(sig, 0.5f)), 2.0f);
  u[gid] = __fsub_rn(1.0f, t);
}

// ---------------------------------------------------------------------------
// K2: exact stable top-k via ranking — R6-verified (326 µs baseline) version:
// full-LDS staging + split-predicate + 4 independent accumulators. CLOSED:
// R7/R8 proved global/hybrid candidate reads are slower; this is at its
// VALU/LDS floor (~30 µs).
// ---------------------------------------------------------------------------
__global__ __launch_bounds__(256) void k_select(const float* __restrict__ u,
                                                const float* __restrict__ rp,
                                                float* __restrict__ pts_out) {
  __shared__ __align__(16) float su[NS];
  int b = blockIdx.x / (NS / 256);
  int blk = blockIdx.x % (NS / 256);
  const float* ub = u + (size_t)b * NS;
  for (int t = threadIdx.x; t < NS / 4; t += 256)
    ((float4*)su)[t] = ((const float4*)ub)[t];
  __syncthreads();
  int i = blk * 256 + (int)threadIdx.x;
  int wb = i & ~63;  // wave-uniform (blk*256 is 64-aligned)
  float ui = su[i];
  int r0 = 0, r1 = 0, r2 = 0, r3 = 0;
  // Phase A: j < wb  ->  count (su[j] >= ui)
  for (int j = 0; j < wb; j += 8) {
    float4 v = *(const float4*)&su[j];
    float4 w = *(const float4*)&su[j + 4];
    r0 += (v.x >= ui) + (w.x >= ui);
    r1 += (v.y >= ui) + (w.y >= ui);
    r2 += (v.z >= ui) + (w.z >= ui);
    r3 += (v.w >= ui) + (w.w >= ui);
  }
  // Boundary chunk: full original predicate over 64 candidates
  for (int j = wb; j < wb + 64; ++j) {
    float vj = su[j];
    r0 += (vj > ui) || (vj == ui && j < i);
  }
  // Phase B: j >= wb+64  ->  count (su[j] > ui)
  for (int j = wb + 64; j < NS; j += 8) {
    float4 v = *(const float4*)&su[j];
    float4 w = *(const float4*)&su[j + 4];
    r0 += (v.x > ui) + (w.x > ui);
    r1 += (v.y > ui) + (w.y > ui);
    r2 += (v.z > ui) + (w.z > ui);
    r3 += (v.w > ui) + (w.w > ui);
  }
  int rank = (r0 + r1) + (r2 + r3);
  if (rank < NU) {
    pts_out[((size_t)b * NP + rank) * 2 + 0] = rp[((size_t)b * NS + i) * 2 + 0];
    pts_out[((size_t)b * NP + rank) * 2 + 1] = rp[((size_t)b * NS + i) * 2 + 1];
  }
}

// K2b: append the random-extra points (R2/R6-verified).
__global__ void k_extra(const float* __restrict__ re, float* __restrict__ pts_out) {
  int gid = blockIdx.x * 256 + threadIdx.x;
  if (gid >= BATCH * NR) return;
  int b = gid / NR, j = gid % NR;
  pts_out[((size_t)b * NP + NU + j) * 2 + 0] = re[(size_t)gid * 2 + 0];
  pts_out[((size_t)b * NP + NU + j) * 2 + 1] = re[(size_t)gid * 2 + 1];
}

// ---------------------------------------------------------------------------
// K3a: per-point bilinear metadata (R6-verified).
// ---------------------------------------------------------------------------
__global__ void k_prep(const float* __restrict__ pts, int2* __restrict__ m2,
                       float4* __restrict__ wts) {
  int g = blockIdx.x * 256 + threadIdx.x;
  if (g >= M_TOT) return;
  float px = pts[(size_t)g * 2 + 0];
  float py = pts[(size_t)g * 2 + 1];
  float x = px * 512.0f - 0.5f;
  float y = py * 512.0f - 0.5f;
  float x0f = floorf(x), y0f = floorf(y);
  float wx = x - x0f, wy = y - y0f;
  int x0 = (int)x0f, y0 = (int)y0f;
  bool vx0 = (unsigned)x0 < (unsigned)HW;
  bool vx1 = (unsigned)(x0 + 1) < (unsigned)HW;
  bool vy0 = (unsigned)y0 < (unsigned)HW;
  bool vy1 = (unsigned)(y0 + 1) < (unsigned)HW;
  int vm = (int)(vx0 && vy0) | ((int)(vx1 && vy0) << 1) |
           ((int)(vx0 && vy1) << 2) | ((int)(vx1 && vy1) << 3);
  m2[g] = make_int2(y0 * HW + x0, vm);
  wts[g] = make_float4((1.0f - wx) * (1.0f - wy), wx * (1.0f - wy),
                       (1.0f - wx) * wy, wx * wy);
}

// ---------------------------------------------------------------------------
// K3b: counting-sort point indices by row (y0) per batch (R3-verified
// correct). Within-bucket order is nondeterministic, but the permutation is
// only used internally and un-applied at k_out — output is identical for any
// perm (GEMM rows are independent; each point's values are bit-identical).
// ---------------------------------------------------------------------------
__global__ __launch_bounds__(512) void k_sort(const int2* __restrict__ m2,
                                              int* __restrict__ perm) {
  __shared__ int hist[512], pref[512];
  int b = blockIdx.x, tid = threadIdx.x;
  hist[tid] = 0;
  __syncthreads();
  for (int p = tid; p < NP; p += 512) {
    int i00 = m2[(size_t)b * NP + p].x;
    int key = min(max(i00, 0), NPLANE - 1) >> 9;  // y0 clamped to [0,511]
    atomicAdd(&hist[key], 1);
  }
  __syncthreads();
  int v = hist[tid];
  pref[tid] = v;
  __syncthreads();
  for (int d = 1; d < 512; d <<= 1) {
    int t = (tid >= d) ? pref[tid - d] : 0;
    __syncthreads();
    pref[tid] += t;
    __syncthreads();
  }
  hist[tid] = pref[tid] - v;  // exclusive prefix -> running offsets
  __syncthreads();
  for (int p = tid; p < NP; p += 512) {
    int i00 = m2[(size_t)b * NP + p].x;
    int key = min(max(i00, 0), NPLANE - 1) >> 9;
    int pos = atomicAdd(&hist[key], 1);
    perm[(size_t)b * NP + pos] = p;
  }
}

// ---------------------------------------------------------------------------
// K3c: materialize metadata in sorted order (coalesced writes; one scattered
// read per point, ~2 MB total). Gather then runs fully coalesced except the
// compulsory plane taps.
// ---------------------------------------------------------------------------
__global__ void k_reorder(const int* __restrict__ perm,
                          const int2* __restrict__ m2,
                          const float4* __restrict__ wts,
                          int2* __restrict__ m2s, float4* __restrict__ wtss) {
  int gid = blockIdx.x * 256 + threadIdx.x;
  if (gid >= M_TOT) return;
  int b = gid / NP;
  int p = perm[gid];  // local index within batch
  m2s[gid] = m2[(size_t)b * NP + p];
  wtss[gid] = wts[(size_t)b * NP + p];
}

// ---------------------------------------------------------------------------
// K3d: gather in SORTED point order (R6's gather3 body, sorted metadata).
// Consecutive lanes now tap adjacent image rows -> ~35% line dedup becomes
// L1/L2-temporal; metadata reads and featsT writes stay coalesced.
// featsT[c][b*NP + s] with s in sorted space.
// ---------------------------------------------------------------------------
__global__ __launch_bounds__(256) void k_gather5(
    const float* __restrict__ fine, const float* __restrict__ coarse,
    const int2* __restrict__ m2s, const float4* __restrict__ wtss,
    float* __restrict__ featsT) {
  int c = blockIdx.x % CIN;
  int rem = blockIdx.x / CIN;
  int b = rem & (BATCH - 1);
  int part = rem >> 2;
  const float* plane = (c < CF_CH)
                           ? fine + ((size_t)b * CF_CH + c) * NPLANE
                           : coarse + ((size_t)b * CC_CH + (c - CF_CH)) * NPLANE;
  const int2* m2b = m2s + (size_t)b * NP;
  const float4* wtsb = wtss + (size_t)b * NP;
  float* outrow = featsT + (size_t)c * M_TOT + (size_t)b * NP;
  int s0 = part * (NP / GCH_SPLIT);
#pragma unroll
  for (int q = 0; q < NP / GCH_SPLIT / 256; ++q) {
    int s = s0 + q * 256 + (int)threadIdx.x;
    int2 mm = m2b[s];
    float4 w = wtsb[s];
    const float* bp = plane + mm.x;
    float t00 = 0.0f, t10 = 0.0f, t01 = 0.0f, t11 = 0.0f;
    if (mm.y & 1) t00 = bp[0] * w.x;
    if (mm.y & 2) t10 = bp[1] * w.y;
    if (mm.y & 4) t01 = bp[HW] * w.z;
    if (mm.y & 8) t11 = bp[HW + 1] * w.w;
    outrow[s] = ((t00 + t10) + t01) + t11;
  }
}

// ---------------------------------------------------------------------------
// K4: GEMM layer 1 from transposed A (At[k][m]), C[M][256] row-major.
// 64x64 tile, BK=32, 256 threads, 4x4 acc. (R6-verified; rows are in sorted
// space — content per row bit-identical.)
// ---------------------------------------------------------------------------
__global__ __launch_bounds__(256) void k_gemm1_At(const float* __restrict__ At,
                                                  const float* __restrict__ W,
                                                  const float* __restrict__ bias,
                                                  float* __restrict__ C) {
  __shared__ __align__(16) float As[32][68];
  __shared__ __align__(16) float Bs[32][68];
  const int bx = blockIdx.x & 3;   // N tile
  const int by = blockIdx.x >> 2;  // M tile
  const int tid = threadIdx.x;
  const int tn = tid & 15, tm = tid >> 4;
  const int m_base = by * 64, n_base = bx * 64;
  float acc[4][4] = {};
  for (int k0 = 0; k0 < CIN; k0 += 32) {
#pragma unroll
    for (int r = 0; r < 2; ++r) {
      int t = tid + r * 256;
      int kk = t >> 4, mg = (t & 15) * 4;
      *(float4*)&As[kk][mg] =
          *(const float4*)&At[(size_t)(k0 + kk) * M_TOT + m_base + mg];
      int row = t >> 3, cg = (t & 7) * 4;
      float4 vw = *(const float4*)&W[(size_t)(n_base + row) * CIN + k0 + cg];
      Bs[cg + 0][row] = vw.x;
      Bs[cg + 1][row] = vw.y;
      Bs[cg + 2][row] = vw.z;
      Bs[cg + 3][row] = vw.w;
    }
    __syncthreads();
#pragma unroll
    for (int kk = 0; kk < 32; ++kk) {
      float4 a4 = *(const float4*)&As[kk][tm * 4];
      float4 b4 = *(const float4*)&Bs[kk][tn * 4];
      float av[4] = {a4.x, a4.y, a4.z, a4.w};
      float bw[4] = {b4.x, b4.y, b4.z, b4.w};
#pragma unroll
      for (int i = 0; i < 4; ++i)
#pragma unroll
        for (int j = 0; j < 4; ++j) acc[i][j] = fmaf(av[i], bw[j], acc[i][j]);
    }
    __syncthreads();
  }
  float bs[4];
#pragma unroll
  for (int j = 0; j < 4; ++j) bs[j] = bias[n_base + tn * 4 + j];
#pragma unroll
  for (int i = 0; i < 4; ++i) {
    float4 o;
    o.x = fmaxf(acc[i][0] + bs[0], 0.0f);
    o.y = fmaxf(acc[i][1] + bs[1], 0.0f);
    o.z = fmaxf(acc[i][2] + bs[2], 0.0f);
    o.w = fmaxf(acc[i][3] + bs[3], 0.0f);
    *(float4*)&C[(size_t)(m_base + tm * 4 + i) * HID + n_base + tn * 4] = o;
  }
}

// ---------------------------------------------------------------------------
// K5: GEMM layer 2 (row-major A). (R6-verified.)
// ---------------------------------------------------------------------------
template <int K>
__global__ __launch_bounds__(256) void k_gemm_relu(const float* __restrict__ A,
                                                   const float* __restrict__ W,
                                                   const float* __restrict__ bias,
                                                   float* __restrict__ C) {
  __shared__ __align__(16) float As[32][68];
  __shared__ __align__(16) float Bs[32][68];
  const int bx = blockIdx.x & 3;
  const int by = blockIdx.x >> 2;
  const int tid = threadIdx.x;
  const int tn = tid & 15, tm = tid >> 4;
  const int m_base = by * 64, n_base = bx * 64;
  float acc[4][4] = {};
  for (int k0 = 0; k0 < K; k0 += 32) {
#pragma unroll
    for (int r = 0; r < 2; ++r) {
      int t = tid + r * 256;
      int row = t >> 3, cg = (t & 7) * 4;
      float4 va = *(const float4*)&A[(size_t)(m_base + row) * K + k0 + cg];
      As[cg + 0][row] = va.x;
      As[cg + 1][row] = va.y;
      As[cg + 2][row] = va.z;
      As[cg + 3][row] = va.w;
      float4 vw = *(const float4*)&W[(size_t)(n_base + row) * K + k0 + cg];
      Bs[cg + 0][row] = vw.x;
      Bs[cg + 1][row] = vw.y;
      Bs[cg + 2][row] = vw.z;
      Bs[cg + 3][row] = vw.w;
    }
    __syncthreads();
#pragma unroll
    for (int kk = 0; kk < 32; ++kk) {
      float4 a4 = *(const float4*)&As[kk][tm * 4];
      float4 b4 = *(const float4*)&Bs[kk][tn * 4];
      float av[4] = {a4.x, a4.y, a4.z, a4.w};
      float bw[4] = {b4.x, b4.y, b4.z, b4.w};
#pragma unroll
      for (int i = 0; i < 4; ++i)
#pragma unroll
        for (int j = 0; j < 4; ++j) acc[i][j] = fmaf(av[i], bw[j], acc[i][j]);
    }
    __syncthreads();
  }
  float bs[4];
#pragma unroll
  for (int j = 0; j < 4; ++j) bs[j] = bias[n_base + tn * 4 + j];
#pragma unroll
  for (int i = 0; i < 4; ++i) {
    float4 o;
    o.x = fmaxf(acc[i][0] + bs[0], 0.0f);
    o.y = fmaxf(acc[i][1] + bs[1], 0.0f);
    o.z = fmaxf(acc[i][2] + bs[2], 0.0f);
    o.w = fmaxf(acc[i][3] + bs[3], 0.0f);
    *(float4*)&C[(size_t)(m_base + tm * 4 + i) * HID + n_base + tn * 4] = o;
  }
}

// ---------------------------------------------------------------------------
// K6: final layer, 4 outputs per point, shuffle reduce; un-permutes the
// sorted point order on the (tiny, 4 MB-granularity) output scatter.
// ---------------------------------------------------------------------------
__global__ __launch_bounds__(256) void k_out(const float* __restrict__ h,
                                             const float* __restrict__ W3,
                                             const float* __restrict__ b3,
                                             const int* __restrict__ perm,
                                             float* __restrict__ out) {
  int gp = blockIdx.x * 4 + (threadIdx.x >> 6);
  int lane = threadIdx.x & 63;
  const float* hr = h + (size_t)gp * HID;
  float4 hv = *(const float4*)&hr[lane * 4];
  float s[4];
#pragma unroll
  for (int o = 0; o < 4; ++o) {
    float4 w = *(const float4*)&W3[o * HID + lane * 4];
    s[o] = hv.x * w.x + hv.y * w.y + hv.z * w.z + hv.w * w.w;
  }
#pragma unroll
  for (int off = 32; off; off >>= 1)
#pragma unroll
    for (int o = 0; o < 4; ++o) s[o] += __shfl_xor(s[o], off, 64);
  if (lane == 0) {
    int b = gp / NP, ns = gp % NP;
    int n = perm[(size_t)b * NP + ns];  // original point index
#pragma unroll
    for (int o = 0; o < 4; ++o)
      out[((size_t)b * OUTC + o) * NP + n] = s[o] + b3[o];
  }
}

extern "C" void kernel_launch(void* const* d_in, const int* in_sizes, int n_in,
                              void* d_out, int out_size, void* d_ws, size_t ws_size,
                              hipStream_t stream) {
  const float* fine = (const float*)d_in[0];
  const float* coarse = (const float*)d_in[1];
  const float* logits = (const float*)d_in[2];
  const float* rand_points = (const float*)d_in[3];
  const float* rand_extra = (const float*)d_in[4];
  const float* W1 = (const float*)d_in[5];
  const float* b1 = (const float*)d_in[6];
  const float* W2 = (const float*)d_in[7];
  const float* b2 = (const float*)d_in[8];
  const float* W3 = (const float*)d_in[9];
  const float* b3 = (const float*)d_in[10];
  float* out = (float*)d_out;

  float* out_logits = out;
  float* out_points = out + (size_t)BATCH * OUTC * NP;

  // ws layout (bytes): u | m2 | wts | m2s | wtss | perm | featsT | h1 | h2
  char* ws = (char*)d_ws;
  float* u = (float*)(ws + 0);               // 196608
  int2* m2 = (int2*)(ws + 196608);           // 131072
  float4* wts = (float4*)(ws + 327680);      // 262144
  int2* m2s = (int2*)(ws + 589824);          // 131072
  float4* wtss = (float4*)(ws + 720896);     // 262144
  int* perm = (int*)(ws + 983040);           // 65536
  float* featsT = (float*)(ws + 1048576);    // 12582912
  float* h1 = (float*)(ws + 13631488);       // 16777216
  float* h2 = (float*)(ws + 30408704);       // 16777216

  k_uncert<<<(BATCH * NS + 255) / 256, 256, 0, stream>>>(logits, rand_points, u);
  k_select<<<BATCH * (NS / 256), 256, 0, stream>>>(u, rand_points, out_points);
  k_extra<<<(BATCH * NR + 255) / 256, 256, 0, stream>>>(rand_extra, out_points);
  k_prep<<<(M_TOT + 255) / 256, 256, 0, stream>>>(out_points, m2, wts);
  k_sort<<<BATCH, 512, 0, stream>>>(m2, perm);
  k_reorder<<<(M_TOT + 255) / 256, 256, 0, stream>>>(perm, m2, wts, m2s, wtss);
  k_gather5<<<CIN * BATCH * GCH_SPLIT, 256, 0, stream>>>(fine, coarse, m2s,
                                                         wtss, featsT);
  k_gemm1_At<<<(M_TOT / 64) * 4, 256, 0, stream>>>(featsT, W1, b1, h1);
  k_gemm_relu<HID><<<(M_TOT / 64) * 4, 256, 0, stream>>>(h1, W2, b2, h2);
  k_out<<<M_TOT / 4, 256, 0, stream>>>(h2, W3, b3, perm, out_logits);
}